// Round 11
// baseline (219.325 us; speedup 1.0000x reference)
//
#include <hip/hip_runtime.h>

#define FIN 128
#define FH  16
#define FO  64
#define GB  128        // nodes per bucket (pow2: bucket = dst>>7)
#define MAXNB 1024     // max buckets (N <= 131072)
#define CHUNK 8192     // edges per block in bscatter (32 KB LDS stage; 391 blocks -> all CUs busy)
#define SLABMAX 8192   // max slab entries staged in LDS by k_nsg (32 KB per buffer)

__device__ __forceinline__ unsigned pack_bf16x2(float a, float b) {
    unsigned ua = __float_as_uint(a), ub = __float_as_uint(b);
    ua = (ua + 0x7fffu + ((ua >> 16) & 1u)) >> 16;          // RNE
    ub = (ub + 0x7fffu + ((ub >> 16) & 1u)) >> 16;
    return ua | (ub << 16);
}

__device__ __forceinline__ float2 unpack_bf16x2(unsigned u) {
    float2 r;
    r.x = __uint_as_float(u << 16);
    r.y = __uint_as_float(u & 0xffff0000u);
    return r;
}

// ---------- A: slab-reserving chunk-local LDS bucket-sort, shfl-scan (proven round-9) ----------
// bucket b owns slab [b*slab, (b+1)*slab).  pack: (dst & 127) << 17 | src  (src < 2^17)
__global__ __launch_bounds__(1024) void k_bscatter(const int* __restrict__ src,
                                                   const int* __restrict__ dst,
                                                   int* __restrict__ bfill,
                                                   int* __restrict__ bedge,
                                                   int E, int slab) {
    __shared__ int h[MAXNB];      // chunk bucket counts -> fill counters (4 KB)
    __shared__ int wtot[16];      // per-wave scan totals
    __shared__ int stage[CHUNK];  // 32 KB
    int t = threadIdx.x;
    int lane = t & 63, w = t >> 6;
    int c0 = blockIdx.x * CHUNK;
    int c1 = min(c0 + CHUNK, E);

    // 1) chunk histogram (int4 edge reads; c0 is a multiple of 4)
    h[t] = 0;
    __syncthreads();
    const int4* dst4 = (const int4*)dst;
    const int4* src4 = (const int4*)src;
    int i4b = c0 >> 2;
    int i4e = (c0 + ((c1 - c0) & ~3)) >> 2;
    for (int i = i4b + t; i < i4e; i += 1024) {
        int4 d = dst4[i];
        atomicAdd(&h[d.x >> 7], 1);
        atomicAdd(&h[d.y >> 7], 1);
        atomicAdd(&h[d.z >> 7], 1);
        atomicAdd(&h[d.w >> 7], 1);
    }
    for (int e = (i4e << 2) + t; e < c1; e += 1024)
        atomicAdd(&h[dst[e] >> 7], 1);
    __syncthreads();

    // 2) exclusive scan over 1024 buckets: wave shfl-scan + cross-wave fixup (2 barriers)
    int a = h[t];
    int incl = a;
#pragma unroll
    for (int off = 1; off < 64; off <<= 1) {
        int u = __shfl_up(incl, off, 64);
        if (lane >= off) incl += u;
    }
    if (lane == 63) wtot[w] = incl;
    __syncthreads();
    int woff = 0;
    for (int j = 0; j < w; ++j) woff += wtot[j];
    int lo = woff + incl - a;

    // 3) reserve slab range directly, clamp overflow
    int r = 0;
    if (a) r = atomicAdd(&bfill[t], a);
    int navail = slab - r; if (navail < 0) navail = 0;
    int hi = lo + min(a, navail);
    h[t] = lo;
    __syncthreads();

    // 4) place packed edges at chunk-local rank (int4 edge reads)
    for (int i = i4b + t; i < i4e; i += 1024) {
        int4 d = dst4[i];
        int4 s = src4[i];
        int p;
        p = atomicAdd(&h[d.x >> 7], 1); stage[p] = ((d.x & 127) << 17) | s.x;
        p = atomicAdd(&h[d.y >> 7], 1); stage[p] = ((d.y & 127) << 17) | s.y;
        p = atomicAdd(&h[d.z >> 7], 1); stage[p] = ((d.z & 127) << 17) | s.z;
        p = atomicAdd(&h[d.w >> 7], 1); stage[p] = ((d.w & 127) << 17) | s.w;
    }
    for (int e = (i4e << 2) + t; e < c1; e += 1024) {
        int d = dst[e];
        int p = atomicAdd(&h[d >> 7], 1);
        stage[p] = ((d & 127) << 17) | src[e];
    }
    __syncthreads();

    // 5) write-out: each thread streams its own bucket's run, int4-vectorized
    int db = t * slab + r - lo;   // bedge[db + p] for p in [lo, hi)
    int p = lo;
    for (; p < hi && ((db + p) & 3); ++p) bedge[db + p] = stage[p];
    for (; p + 3 < hi; p += 4) {
        int4 v;
        v.x = stage[p]; v.y = stage[p + 1]; v.z = stage[p + 2]; v.w = stage[p + 3];
        *(int4*)(bedge + db + p) = v;
    }
    for (; p < hi; ++p) bedge[db + p] = stage[p];
}

// ---------- B: fused nsort + layer-1 GEMM; slab staged in LDS, sorted in LDS (proven round-9) ----------
__global__ __launch_bounds__(512) void k_nsg(const int* __restrict__ bfill,
                                             const int* __restrict__ bedge,
                                             const float* __restrict__ x,
                                             const float* __restrict__ W1,
                                             int* __restrict__ sorted_src,
                                             int* __restrict__ counts,
                                             int* __restrict__ row_start,
                                             float* __restrict__ dinv,
                                             uint2* __restrict__ hs1u2,
                                             int N, int slab) {
    __shared__ int4 stageL4[SLABMAX / 4];  // 32 KB raw slab
    __shared__ int4 stage24[SLABMAX / 4];  // 32 KB node-sorted src
    __shared__ int hist[GB];
    __shared__ int fill[GB];
    __shared__ float dinvL[GB];
    __shared__ int wtot2[2];
    __shared__ float4 w4[FIN * FH / 4];    // 8 KB
    int* stageL = (int*)stageL4;
    int* stage2 = (int*)stage24;
    int t = threadIdx.x, b = blockIdx.x;
    int lane = t & 63, w = t >> 6;
    int base = b << 7;
    int nn = min(GB, N - base);
    if (nn <= 0) return;

    int ebeg = b * slab;
    int cnt0 = min(bfill[b], slab);
    int c4 = cnt0 >> 2;

    // stage slab -> LDS (coalesced int4); also W1 -> LDS; hist init
    const int4* g4 = (const int4*)(bedge + ebeg);   // ebeg 16B-aligned (slab % 16 == 0)
    for (int i = t; i < c4; i += 512) stageL4[i] = g4[i];
    for (int e = (c4 << 2) + t; e < cnt0; e += 512) stageL[e] = bedge[ebeg + e];
    if (t < GB) hist[t] = 0;
    for (int i = t; i < FIN * FH / 4; i += 512) w4[i] = ((const float4*)W1)[i];
    __syncthreads();

    // histogram from LDS
    for (int i = t; i < c4; i += 512) {
        int4 v = stageL4[i];
        atomicAdd(&hist[v.x >> 17], 1);
        atomicAdd(&hist[v.y >> 17], 1);
        atomicAdd(&hist[v.z >> 17], 1);
        atomicAdd(&hist[v.w >> 17], 1);
    }
    for (int e = (c4 << 2) + t; e < cnt0; e += 512)
        atomicAdd(&hist[stageL[e] >> 17], 1);
    __syncthreads();

    // exclusive scan over 128 counts: wave shfl-scan (threads 0..127 = 2 waves) + fixup
    int c = (t < GB) ? hist[t] : 0;
    int incl = c;
#pragma unroll
    for (int off = 1; off < 64; off <<= 1) {
        int u = __shfl_up(incl, off, 64);
        if (lane >= off) incl += u;
    }
    if (t < GB && lane == 63) wtot2[w] = incl;
    __syncthreads();
    int excl = incl - c + ((w == 1 && t < GB) ? wtot2[0] : 0);
    if (t < nn) {
        counts[base + t] = c;
        row_start[base + t] = ebeg + excl;
        float dv = rsqrtf((float)(c + 1));
        dinv[base + t] = dv;
        dinvL[t] = dv;
        fill[t] = excl;        // LOCAL offset into stage2
    }
    __syncthreads();

    // node-scatter within LDS (random LDS writes, cheap)
    for (int i = t; i < c4; i += 512) {
        int4 v = stageL4[i];
        int p;
        p = atomicAdd(&fill[v.x >> 17], 1); stage2[p] = v.x & 0x1FFFF;
        p = atomicAdd(&fill[v.y >> 17], 1); stage2[p] = v.y & 0x1FFFF;
        p = atomicAdd(&fill[v.z >> 17], 1); stage2[p] = v.z & 0x1FFFF;
        p = atomicAdd(&fill[v.w >> 17], 1); stage2[p] = v.w & 0x1FFFF;
    }
    for (int e = (c4 << 2) + t; e < cnt0; e += 512) {
        int v = stageL[e];
        int p = atomicAdd(&fill[v >> 17], 1);
        stage2[p] = v & 0x1FFFF;
    }
    __syncthreads();

    // stream sorted_src out coalesced (int4)
    int4* o4 = (int4*)(sorted_src + ebeg);
    for (int i = t; i < c4; i += 512) o4[i] = stage24[i];
    for (int e = (c4 << 2) + t; e < cnt0; e += 512) sorted_src[ebeg + e] = stage2[e];

    // ---- phase 2: gemm1, 1 row x 4 features per thread (no barrier needed: w4/dinvL ready) ----
    int fg = t & 3, rg = t >> 2;           // rg: 0..127
    if (rg >= nn) return;
    int r0 = base + rg;
    const float4* xa4 = (const float4*)(x + (long long)r0 * FIN);
    float4 a0 = make_float4(0.f, 0.f, 0.f, 0.f);
#pragma unroll 4
    for (int k4 = 0; k4 < FIN / 4; ++k4) {
        float4 xa = xa4[k4];
        const float4* wp = &w4[k4 * 16 + fg];
        float4 w0 = wp[0], w1 = wp[4], w2 = wp[8], w3 = wp[12];
        a0.x = fmaf(xa.x, w0.x, a0.x); a0.y = fmaf(xa.x, w0.y, a0.y);
        a0.z = fmaf(xa.x, w0.z, a0.z); a0.w = fmaf(xa.x, w0.w, a0.w);
        a0.x = fmaf(xa.y, w1.x, a0.x); a0.y = fmaf(xa.y, w1.y, a0.y);
        a0.z = fmaf(xa.y, w1.z, a0.z); a0.w = fmaf(xa.y, w1.w, a0.w);
        a0.x = fmaf(xa.z, w2.x, a0.x); a0.y = fmaf(xa.z, w2.y, a0.y);
        a0.z = fmaf(xa.z, w2.z, a0.z); a0.w = fmaf(xa.z, w2.w, a0.w);
        a0.x = fmaf(xa.w, w3.x, a0.x); a0.y = fmaf(xa.w, w3.y, a0.y);
        a0.z = fmaf(xa.w, w3.z, a0.z); a0.w = fmaf(xa.w, w3.w, a0.w);
    }
    float d0 = dinvL[rg];
    uint2 o0;
    o0.x = pack_bf16x2(a0.x * d0, a0.y * d0);
    o0.y = pack_bf16x2(a0.z * d0, a0.w * d0);
    hs1u2[r0 * 4 + fg] = o0;
}

// ---------- layer 1 gather: 8 nodes per wave (8 lanes/node = 8 f2 slots; no reduce) ----------
__global__ __launch_bounds__(256) void k_gather1(const int* __restrict__ rs,
                                                 const int* __restrict__ cnt,
                                                 const int* __restrict__ ss,
                                                 const unsigned* __restrict__ hs1u,
                                                 const float* __restrict__ dinv,
                                                 const float* __restrict__ b1,
                                                 unsigned* __restrict__ h1su, int n) {
    int t = threadIdx.x;
    int lane = t & 63;
    int f2 = lane & 7;
    int node = blockIdx.x * 32 + ((t >> 6) << 3) + (lane >> 3);
    bool act = (node < n);
    int beg = 0, end = 0;
    unsigned uself = 0;
    float di = 0.0f;
    if (act) {
        beg = rs[node]; end = beg + cnt[node];
        uself = hs1u[node * 8 + f2];   // issue early (independent)
        di = dinv[node];
    }
    float ax = 0.0f, ay = 0.0f;
    int e = beg;
    for (; e + 7 < end; e += 8) {
        int s0 = ss[e],     s1 = ss[e + 1], s2 = ss[e + 2], s3 = ss[e + 3];
        int s4 = ss[e + 4], s5 = ss[e + 5], s6 = ss[e + 6], s7 = ss[e + 7];
        unsigned u0 = hs1u[s0 * 8 + f2], u1 = hs1u[s1 * 8 + f2];
        unsigned u2 = hs1u[s2 * 8 + f2], u3 = hs1u[s3 * 8 + f2];
        unsigned u4 = hs1u[s4 * 8 + f2], u5 = hs1u[s5 * 8 + f2];
        unsigned u6 = hs1u[s6 * 8 + f2], u7 = hs1u[s7 * 8 + f2];
        float2 p0 = unpack_bf16x2(u0), p1 = unpack_bf16x2(u1);
        float2 p2 = unpack_bf16x2(u2), p3 = unpack_bf16x2(u3);
        float2 p4 = unpack_bf16x2(u4), p5 = unpack_bf16x2(u5);
        float2 p6 = unpack_bf16x2(u6), p7 = unpack_bf16x2(u7);
        ax += ((p0.x + p1.x) + (p2.x + p3.x)) + ((p4.x + p5.x) + (p6.x + p7.x));
        ay += ((p0.y + p1.y) + (p2.y + p3.y)) + ((p4.y + p5.y) + (p6.y + p7.y));
    }
    for (; e + 3 < end; e += 4) {
        int s0 = ss[e], s1 = ss[e + 1], s2 = ss[e + 2], s3 = ss[e + 3];
        unsigned u0 = hs1u[s0 * 8 + f2], u1 = hs1u[s1 * 8 + f2];
        unsigned u2 = hs1u[s2 * 8 + f2], u3 = hs1u[s3 * 8 + f2];
        float2 p0 = unpack_bf16x2(u0), p1 = unpack_bf16x2(u1);
        float2 p2 = unpack_bf16x2(u2), p3 = unpack_bf16x2(u3);
        ax += (p0.x + p1.x) + (p2.x + p3.x);
        ay += (p0.y + p1.y) + (p2.y + p3.y);
    }
    for (; e + 1 < end; e += 2) {
        int s0 = ss[e], s1 = ss[e + 1];
        unsigned u0 = hs1u[s0 * 8 + f2], u1 = hs1u[s1 * 8 + f2];
        float2 p0 = unpack_bf16x2(u0), p1 = unpack_bf16x2(u1);
        ax += p0.x + p1.x; ay += p0.y + p1.y;
    }
    if (e < end) {
        float2 p = unpack_bf16x2(hs1u[ss[e] * 8 + f2]);
        ax += p.x; ay += p.y;
    }
    if (act) {
        float2 s = unpack_bf16x2(uself);  // self-loop
        ax += s.x; ay += s.y;
        float2 bb = ((const float2*)b1)[f2];
        float v0 = fmaxf(fmaf(di, ax, bb.x), 0.0f) * di;
        float v1 = fmaxf(fmaf(di, ay, bb.y), 0.0f) * di;
        h1su[node * 8 + f2] = pack_bf16x2(v0, v1);
    }
}

// ---------- layer 2: 8 nodes per wave; gather + (g @ W2)*dinv + b2 -> log_softmax ----------
// 8 lanes/node (no reduce); epilogue: each lane computes 8 output columns l8+8k in 4 passes
__global__ __launch_bounds__(256) void k_agg2f(const int* __restrict__ rs,
                                               const int* __restrict__ cnt,
                                               const int* __restrict__ ss,
                                               const unsigned* __restrict__ h1su,
                                               const float* __restrict__ dinv,
                                               const float* __restrict__ W2,
                                               const float* __restrict__ b2,
                                               float* __restrict__ out, int n) {
    int t = threadIdx.x;
    int lane = t & 63;
    int l8 = lane & 7, f2 = l8;
    int node = blockIdx.x * 32 + ((t >> 6) << 3) + (lane >> 3);
    bool act = (node < n);
    int beg = 0, end = 0;
    unsigned uself = 0;
    float di = 0.0f;
    if (act) {
        beg = rs[node]; end = beg + cnt[node];
        uself = h1su[node * 8 + f2];   // issue early (independent)
        di = dinv[node];
    }
    float ax = 0.0f, ay = 0.0f;
    int e = beg;
    for (; e + 7 < end; e += 8) {
        int s0 = ss[e],     s1 = ss[e + 1], s2 = ss[e + 2], s3 = ss[e + 3];
        int s4 = ss[e + 4], s5 = ss[e + 5], s6 = ss[e + 6], s7 = ss[e + 7];
        unsigned u0 = h1su[s0 * 8 + f2], u1 = h1su[s1 * 8 + f2];
        unsigned u2 = h1su[s2 * 8 + f2], u3 = h1su[s3 * 8 + f2];
        unsigned u4 = h1su[s4 * 8 + f2], u5 = h1su[s5 * 8 + f2];
        unsigned u6 = h1su[s6 * 8 + f2], u7 = h1su[s7 * 8 + f2];
        float2 p0 = unpack_bf16x2(u0), p1 = unpack_bf16x2(u1);
        float2 p2 = unpack_bf16x2(u2), p3 = unpack_bf16x2(u3);
        float2 p4 = unpack_bf16x2(u4), p5 = unpack_bf16x2(u5);
        float2 p6 = unpack_bf16x2(u6), p7 = unpack_bf16x2(u7);
        ax += ((p0.x + p1.x) + (p2.x + p3.x)) + ((p4.x + p5.x) + (p6.x + p7.x));
        ay += ((p0.y + p1.y) + (p2.y + p3.y)) + ((p4.y + p5.y) + (p6.y + p7.y));
    }
    for (; e + 3 < end; e += 4) {
        int s0 = ss[e], s1 = ss[e + 1], s2 = ss[e + 2], s3 = ss[e + 3];
        unsigned u0 = h1su[s0 * 8 + f2], u1 = h1su[s1 * 8 + f2];
        unsigned u2 = h1su[s2 * 8 + f2], u3 = h1su[s3 * 8 + f2];
        float2 p0 = unpack_bf16x2(u0), p1 = unpack_bf16x2(u1);
        float2 p2 = unpack_bf16x2(u2), p3 = unpack_bf16x2(u3);
        ax += (p0.x + p1.x) + (p2.x + p3.x);
        ay += (p0.y + p1.y) + (p2.y + p3.y);
    }
    for (; e + 1 < end; e += 2) {
        int s0 = ss[e], s1 = ss[e + 1];
        unsigned u0 = h1su[s0 * 8 + f2], u1 = h1su[s1 * 8 + f2];
        float2 p0 = unpack_bf16x2(u0), p1 = unpack_bf16x2(u1);
        ax += p0.x + p1.x; ay += p0.y + p1.y;
    }
    if (e < end) {
        float2 p = unpack_bf16x2(h1su[ss[e] * 8 + f2]);
        ax += p.x; ay += p.y;
    }
    float2 s = unpack_bf16x2(uself);  // self-loop (0 for inactive)
    ax += s.x; ay += s.y;
    // g row broadcast into 16 regs (each 8-lane group holds its node's full row)
    float gg[FH];
#pragma unroll
    for (int j = 0; j < 8; ++j) {
        gg[2 * j]     = __shfl(ax, j, 8);
        gg[2 * j + 1] = __shfl(ay, j, 8);
    }
    // 4 passes x 2 columns: cols l8 + 16*p and l8 + 8 + 16*p (reuse w0/w1 regs)
    float o[8];
    float w0[FH], w1[FH];
#pragma unroll
    for (int p = 0; p < 4; ++p) {
        int c0 = l8 + 16 * p, c1 = c0 + 8;
#pragma unroll
        for (int j = 0; j < FH; ++j) {
            w0[j] = W2[j * FO + c0];
            w1[j] = W2[j * FO + c1];
        }
        float oa = 0.0f, ob = 0.0f;
#pragma unroll
        for (int j = 0; j < FH; ++j) {
            oa = fmaf(gg[j], w0[j], oa);
            ob = fmaf(gg[j], w1[j], ob);
        }
        o[2 * p]     = fmaf(di, oa, b2[c0]);
        o[2 * p + 1] = fmaf(di, ob, b2[c1]);
    }
    // log_softmax over 64 outputs = 8 regs x 8 lanes (xor offsets 4,2,1 stay in group)
    float m = o[0];
#pragma unroll
    for (int k = 1; k < 8; ++k) m = fmaxf(m, o[k]);
#pragma unroll
    for (int off = 4; off >= 1; off >>= 1) m = fmaxf(m, __shfl_xor(m, off, 64));
    float ex = 0.0f;
#pragma unroll
    for (int k = 0; k < 8; ++k) ex += __expf(o[k] - m);
#pragma unroll
    for (int off = 4; off >= 1; off >>= 1) ex += __shfl_xor(ex, off, 64);
    float lse = m + __logf(ex);
    if (act) {
        float* orow = out + (long long)node * FO;
        // column for o[2p] is l8+16p, for o[2p+1] is l8+8+16p
#pragma unroll
        for (int p = 0; p < 4; ++p) {
            orow[l8 + 16 * p]     = o[2 * p]     - lse;
            orow[l8 + 8 + 16 * p] = o[2 * p + 1] - lse;
        }
    }
}

extern "C" void kernel_launch(void* const* d_in, const int* in_sizes, int n_in,
                              void* d_out, int out_size, void* d_ws, size_t ws_size,
                              hipStream_t stream) {
    const float* x  = (const float*)d_in[0];
    const int*   ei = (const int*)d_in[1];
    const float* W1 = (const float*)d_in[2];
    const float* b1 = (const float*)d_in[3];
    const float* W2 = (const float*)d_in[4];
    const float* b2 = (const float*)d_in[5];
    float* out = (float*)d_out;

    int N = in_sizes[0] / FIN;   // 100000
    int E = in_sizes[1] / 2;     // 3200000
    const int* src = ei;
    const int* dst = ei + E;
    int nb = (N + GB - 1) / GB;  // 782

    // slab size per bucket: mean + 25% + 1024 (>20 sigma for uniform dst), 16-rounded,
    // clamped to the LDS staging capacity of k_nsg
    int slab = (E + nb - 1) / nb;
    slab = slab + slab / 4 + 1024;
    slab = (slab + 15) & ~15;
    if (slab > SLABMAX) slab = SLABMAX;
    long long slabtot = (long long)nb * slab;

    // workspace (4B units), hs1u/h1su FIRST (16B-aligned):
    //   hs1u[8N] | h1su[8N] | bfill[1024] | counts[N] | row_start[N]
    //   | sorted_src[nb*slab] | bedge[nb*slab] | dinv[N]
    unsigned* hs1u  = (unsigned*)d_ws;
    unsigned* h1su  = hs1u + 8LL * N;
    int* bfill      = (int*)(h1su + 8LL * N);
    int* counts     = bfill + MAXNB;
    int* row_start  = counts + N;
    int* sorted_src = row_start + N;
    int* bedge      = sorted_src + slabtot;
    float* dinv     = (float*)(bedge + slabtot);

    hipMemsetAsync(bfill, 0, MAXNB * sizeof(int), stream);
    k_bscatter<<<(E + CHUNK - 1) / CHUNK, 1024, 0, stream>>>(src, dst, bfill, bedge, E, slab);
    k_nsg<<<nb, 512, 0, stream>>>(bfill, bedge, x, W1, sorted_src, counts, row_start,
                                  dinv, (uint2*)hs1u, N, slab);
    k_gather1<<<(N + 31) / 32, 256, 0, stream>>>(row_start, counts, sorted_src, hs1u, dinv, b1, h1su, N);
    k_agg2f<<<(N + 31) / 32, 256, 0, stream>>>(row_start, counts, sorted_src, h1su, dinv, W2, b2, out, N);
}

// Round 12
// 215.463 us; speedup vs baseline: 1.0179x; 1.0179x over previous
//
#include <hip/hip_runtime.h>

#define FIN 128
#define FH  16
#define FO  64
#define GB  128        // nodes per bucket (pow2: bucket = dst>>7)
#define MAXNB 1024     // max buckets (N <= 131072)
#define CHUNK 8192     // edges per block in bscatter (32 KB LDS stage; 391 blocks -> all CUs busy)
#define SLABMAX 8192   // max slab entries staged in LDS by k_nsg (32 KB per buffer)

__device__ __forceinline__ unsigned pack_bf16x2(float a, float b) {
    unsigned ua = __float_as_uint(a), ub = __float_as_uint(b);
    ua = (ua + 0x7fffu + ((ua >> 16) & 1u)) >> 16;          // RNE
    ub = (ub + 0x7fffu + ((ub >> 16) & 1u)) >> 16;
    return ua | (ub << 16);
}

__device__ __forceinline__ float2 unpack_bf16x2(unsigned u) {
    float2 r;
    r.x = __uint_as_float(u << 16);
    r.y = __uint_as_float(u & 0xffff0000u);
    return r;
}

// ---------- A: slab-reserving chunk-local LDS bucket-sort, shfl-scan (proven round-9) ----------
// bucket b owns slab [b*slab, (b+1)*slab).  pack: (dst & 127) << 17 | src  (src < 2^17)
__global__ __launch_bounds__(1024) void k_bscatter(const int* __restrict__ src,
                                                   const int* __restrict__ dst,
                                                   int* __restrict__ bfill,
                                                   int* __restrict__ bedge,
                                                   int E, int slab) {
    __shared__ int h[MAXNB];      // chunk bucket counts -> fill counters (4 KB)
    __shared__ int wtot[16];      // per-wave scan totals
    __shared__ int stage[CHUNK];  // 32 KB
    int t = threadIdx.x;
    int lane = t & 63, w = t >> 6;
    int c0 = blockIdx.x * CHUNK;
    int c1 = min(c0 + CHUNK, E);

    // 1) chunk histogram (int4 edge reads; c0 is a multiple of 4)
    h[t] = 0;
    __syncthreads();
    const int4* dst4 = (const int4*)dst;
    const int4* src4 = (const int4*)src;
    int i4b = c0 >> 2;
    int i4e = (c0 + ((c1 - c0) & ~3)) >> 2;
    for (int i = i4b + t; i < i4e; i += 1024) {
        int4 d = dst4[i];
        atomicAdd(&h[d.x >> 7], 1);
        atomicAdd(&h[d.y >> 7], 1);
        atomicAdd(&h[d.z >> 7], 1);
        atomicAdd(&h[d.w >> 7], 1);
    }
    for (int e = (i4e << 2) + t; e < c1; e += 1024)
        atomicAdd(&h[dst[e] >> 7], 1);
    __syncthreads();

    // 2) exclusive scan over 1024 buckets: wave shfl-scan + cross-wave fixup (2 barriers)
    int a = h[t];
    int incl = a;
#pragma unroll
    for (int off = 1; off < 64; off <<= 1) {
        int u = __shfl_up(incl, off, 64);
        if (lane >= off) incl += u;
    }
    if (lane == 63) wtot[w] = incl;
    __syncthreads();
    int woff = 0;
    for (int j = 0; j < w; ++j) woff += wtot[j];
    int lo = woff + incl - a;

    // 3) reserve slab range directly, clamp overflow
    int r = 0;
    if (a) r = atomicAdd(&bfill[t], a);
    int navail = slab - r; if (navail < 0) navail = 0;
    int hi = lo + min(a, navail);
    h[t] = lo;
    __syncthreads();

    // 4) place packed edges at chunk-local rank (int4 edge reads)
    for (int i = i4b + t; i < i4e; i += 1024) {
        int4 d = dst4[i];
        int4 s = src4[i];
        int p;
        p = atomicAdd(&h[d.x >> 7], 1); stage[p] = ((d.x & 127) << 17) | s.x;
        p = atomicAdd(&h[d.y >> 7], 1); stage[p] = ((d.y & 127) << 17) | s.y;
        p = atomicAdd(&h[d.z >> 7], 1); stage[p] = ((d.z & 127) << 17) | s.z;
        p = atomicAdd(&h[d.w >> 7], 1); stage[p] = ((d.w & 127) << 17) | s.w;
    }
    for (int e = (i4e << 2) + t; e < c1; e += 1024) {
        int d = dst[e];
        int p = atomicAdd(&h[d >> 7], 1);
        stage[p] = ((d & 127) << 17) | src[e];
    }
    __syncthreads();

    // 5) write-out: each thread streams its own bucket's run, int4-vectorized
    int db = t * slab + r - lo;   // bedge[db + p] for p in [lo, hi)
    int p = lo;
    for (; p < hi && ((db + p) & 3); ++p) bedge[db + p] = stage[p];
    for (; p + 3 < hi; p += 4) {
        int4 v;
        v.x = stage[p]; v.y = stage[p + 1]; v.z = stage[p + 2]; v.w = stage[p + 3];
        *(int4*)(bedge + db + p) = v;
    }
    for (; p < hi; ++p) bedge[db + p] = stage[p];
}

// ---------- B: fused nsort + layer-1 GEMM; slab staged in LDS, sorted in LDS (proven round-9) ----------
__global__ __launch_bounds__(512) void k_nsg(const int* __restrict__ bfill,
                                             const int* __restrict__ bedge,
                                             const float* __restrict__ x,
                                             const float* __restrict__ W1,
                                             int* __restrict__ sorted_src,
                                             int* __restrict__ counts,
                                             int* __restrict__ row_start,
                                             float* __restrict__ dinv,
                                             uint2* __restrict__ hs1u2,
                                             int N, int slab) {
    __shared__ int4 stageL4[SLABMAX / 4];  // 32 KB raw slab
    __shared__ int4 stage24[SLABMAX / 4];  // 32 KB node-sorted src
    __shared__ int hist[GB];
    __shared__ int fill[GB];
    __shared__ float dinvL[GB];
    __shared__ int wtot2[2];
    __shared__ float4 w4[FIN * FH / 4];    // 8 KB
    int* stageL = (int*)stageL4;
    int* stage2 = (int*)stage24;
    int t = threadIdx.x, b = blockIdx.x;
    int lane = t & 63, w = t >> 6;
    int base = b << 7;
    int nn = min(GB, N - base);
    if (nn <= 0) return;

    int ebeg = b * slab;
    int cnt0 = min(bfill[b], slab);
    int c4 = cnt0 >> 2;

    // stage slab -> LDS (coalesced int4); also W1 -> LDS; hist init
    const int4* g4 = (const int4*)(bedge + ebeg);   // ebeg 16B-aligned (slab % 16 == 0)
    for (int i = t; i < c4; i += 512) stageL4[i] = g4[i];
    for (int e = (c4 << 2) + t; e < cnt0; e += 512) stageL[e] = bedge[ebeg + e];
    if (t < GB) hist[t] = 0;
    for (int i = t; i < FIN * FH / 4; i += 512) w4[i] = ((const float4*)W1)[i];
    __syncthreads();

    // histogram from LDS
    for (int i = t; i < c4; i += 512) {
        int4 v = stageL4[i];
        atomicAdd(&hist[v.x >> 17], 1);
        atomicAdd(&hist[v.y >> 17], 1);
        atomicAdd(&hist[v.z >> 17], 1);
        atomicAdd(&hist[v.w >> 17], 1);
    }
    for (int e = (c4 << 2) + t; e < cnt0; e += 512)
        atomicAdd(&hist[stageL[e] >> 17], 1);
    __syncthreads();

    // exclusive scan over 128 counts: wave shfl-scan (threads 0..127 = 2 waves) + fixup
    int c = (t < GB) ? hist[t] : 0;
    int incl = c;
#pragma unroll
    for (int off = 1; off < 64; off <<= 1) {
        int u = __shfl_up(incl, off, 64);
        if (lane >= off) incl += u;
    }
    if (t < GB && lane == 63) wtot2[w] = incl;
    __syncthreads();
    int excl = incl - c + ((w == 1 && t < GB) ? wtot2[0] : 0);
    if (t < nn) {
        counts[base + t] = c;
        row_start[base + t] = ebeg + excl;
        float dv = rsqrtf((float)(c + 1));
        dinv[base + t] = dv;
        dinvL[t] = dv;
        fill[t] = excl;        // LOCAL offset into stage2
    }
    __syncthreads();

    // node-scatter within LDS (random LDS writes, cheap)
    for (int i = t; i < c4; i += 512) {
        int4 v = stageL4[i];
        int p;
        p = atomicAdd(&fill[v.x >> 17], 1); stage2[p] = v.x & 0x1FFFF;
        p = atomicAdd(&fill[v.y >> 17], 1); stage2[p] = v.y & 0x1FFFF;
        p = atomicAdd(&fill[v.z >> 17], 1); stage2[p] = v.z & 0x1FFFF;
        p = atomicAdd(&fill[v.w >> 17], 1); stage2[p] = v.w & 0x1FFFF;
    }
    for (int e = (c4 << 2) + t; e < cnt0; e += 512) {
        int v = stageL[e];
        int p = atomicAdd(&fill[v >> 17], 1);
        stage2[p] = v & 0x1FFFF;
    }
    __syncthreads();

    // stream sorted_src out coalesced (int4)
    int4* o4 = (int4*)(sorted_src + ebeg);
    for (int i = t; i < c4; i += 512) o4[i] = stage24[i];
    for (int e = (c4 << 2) + t; e < cnt0; e += 512) sorted_src[ebeg + e] = stage2[e];

    // ---- phase 2: gemm1, 1 row x 4 features per thread (no barrier needed: w4/dinvL ready) ----
    int fg = t & 3, rg = t >> 2;           // rg: 0..127
    if (rg >= nn) return;
    int r0 = base + rg;
    const float4* xa4 = (const float4*)(x + (long long)r0 * FIN);
    float4 a0 = make_float4(0.f, 0.f, 0.f, 0.f);
#pragma unroll 4
    for (int k4 = 0; k4 < FIN / 4; ++k4) {
        float4 xa = xa4[k4];
        const float4* wp = &w4[k4 * 16 + fg];
        float4 w0 = wp[0], w1 = wp[4], w2 = wp[8], w3 = wp[12];
        a0.x = fmaf(xa.x, w0.x, a0.x); a0.y = fmaf(xa.x, w0.y, a0.y);
        a0.z = fmaf(xa.x, w0.z, a0.z); a0.w = fmaf(xa.x, w0.w, a0.w);
        a0.x = fmaf(xa.y, w1.x, a0.x); a0.y = fmaf(xa.y, w1.y, a0.y);
        a0.z = fmaf(xa.y, w1.z, a0.z); a0.w = fmaf(xa.y, w1.w, a0.w);
        a0.x = fmaf(xa.z, w2.x, a0.x); a0.y = fmaf(xa.z, w2.y, a0.y);
        a0.z = fmaf(xa.z, w2.z, a0.z); a0.w = fmaf(xa.z, w2.w, a0.w);
        a0.x = fmaf(xa.w, w3.x, a0.x); a0.y = fmaf(xa.w, w3.y, a0.y);
        a0.z = fmaf(xa.w, w3.z, a0.z); a0.w = fmaf(xa.w, w3.w, a0.w);
    }
    float d0 = dinvL[rg];
    uint2 o0;
    o0.x = pack_bf16x2(a0.x * d0, a0.y * d0);
    o0.y = pack_bf16x2(a0.z * d0, a0.w * d0);
    hs1u2[r0 * 4 + fg] = o0;
}

// ---------- layer 1 gather: 4 nodes/wave, uint2 rows (4 f4-lanes x 4 edge-groups, 8-deep) ----------
__global__ __launch_bounds__(256) void k_gather1(const int* __restrict__ rs,
                                                 const int* __restrict__ cnt,
                                                 const int* __restrict__ ss,
                                                 const uint2* __restrict__ hs1u2,
                                                 const float* __restrict__ dinv,
                                                 const float* __restrict__ b1,
                                                 uint2* __restrict__ h1su2, int n) {
    int t = threadIdx.x;
    int lane = t & 63;
    int l16 = lane & 15, f4 = l16 & 3, g4 = l16 >> 2;
    int node = blockIdx.x * 16 + ((t >> 6) << 2) + (lane >> 4);
    bool act = (node < n);
    int beg = 0, end = 0;
    uint2 uself = make_uint2(0u, 0u);
    float di = 0.0f;
    if (act) {
        beg = rs[node]; end = beg + cnt[node];
        uself = hs1u2[node * 4 + f4];   // issue early (independent)
        di = dinv[node];
    }
    float4 acc = make_float4(0.f, 0.f, 0.f, 0.f);
    int e = beg + g4;
    for (; e + 28 < end; e += 32) {                 // 32 edges/node per iteration
        int s0 = ss[e],      s1 = ss[e + 4],  s2 = ss[e + 8],  s3 = ss[e + 12];
        int s4 = ss[e + 16], s5 = ss[e + 20], s6 = ss[e + 24], s7 = ss[e + 28];
        uint2 u0 = hs1u2[s0 * 4 + f4], u1 = hs1u2[s1 * 4 + f4];
        uint2 u2 = hs1u2[s2 * 4 + f4], u3 = hs1u2[s3 * 4 + f4];
        uint2 u4 = hs1u2[s4 * 4 + f4], u5 = hs1u2[s5 * 4 + f4];
        uint2 u6 = hs1u2[s6 * 4 + f4], u7 = hs1u2[s7 * 4 + f4];
#define ACC2(U) { float2 pa = unpack_bf16x2((U).x), pb = unpack_bf16x2((U).y); \
                  acc.x += pa.x; acc.y += pa.y; acc.z += pb.x; acc.w += pb.y; }
        ACC2(u0) ACC2(u1) ACC2(u2) ACC2(u3) ACC2(u4) ACC2(u5) ACC2(u6) ACC2(u7)
    }
    for (; e + 4 < end; e += 8) {
        int s0 = ss[e], s1 = ss[e + 4];
        uint2 u0 = hs1u2[s0 * 4 + f4], u1 = hs1u2[s1 * 4 + f4];
        ACC2(u0) ACC2(u1)
    }
    if (e < end) {
        uint2 u0 = hs1u2[ss[e] * 4 + f4];
        ACC2(u0)
    }
    // reduce across 4 edge-groups (lane bits 2,3 -- stays within each 16-lane node-group)
    acc.x += __shfl_xor(acc.x, 4, 64); acc.y += __shfl_xor(acc.y, 4, 64);
    acc.z += __shfl_xor(acc.z, 4, 64); acc.w += __shfl_xor(acc.w, 4, 64);
    acc.x += __shfl_xor(acc.x, 8, 64); acc.y += __shfl_xor(acc.y, 8, 64);
    acc.z += __shfl_xor(acc.z, 8, 64); acc.w += __shfl_xor(acc.w, 8, 64);
    if (act) {
        float2 sa = unpack_bf16x2(uself.x), sb = unpack_bf16x2(uself.y);  // self-loop
        acc.x += sa.x; acc.y += sa.y; acc.z += sb.x; acc.w += sb.y;
        float4 bb = ((const float4*)b1)[f4];
        float v0 = fmaxf(fmaf(di, acc.x, bb.x), 0.0f) * di;
        float v1 = fmaxf(fmaf(di, acc.y, bb.y), 0.0f) * di;
        float v2 = fmaxf(fmaf(di, acc.z, bb.z), 0.0f) * di;
        float v3 = fmaxf(fmaf(di, acc.w, bb.w), 0.0f) * di;
        if (l16 < 4) h1su2[node * 4 + f4] = make_uint2(pack_bf16x2(v0, v1), pack_bf16x2(v2, v3));
    }
}

// ---------- layer 2: 4 nodes/wave, uint2 rows; gather + (g @ W2)*dinv + b2 -> log_softmax ----------
__global__ __launch_bounds__(256) void k_agg2f(const int* __restrict__ rs,
                                               const int* __restrict__ cnt,
                                               const int* __restrict__ ss,
                                               const uint2* __restrict__ h1su2,
                                               const float* __restrict__ dinv,
                                               const float* __restrict__ W2,
                                               const float* __restrict__ b2,
                                               float* __restrict__ out, int n) {
    int t = threadIdx.x;
    int lane = t & 63;
    int l16 = lane & 15, f4 = l16 & 3, g4 = l16 >> 2;
    int node = blockIdx.x * 16 + ((t >> 6) << 2) + (lane >> 4);
    bool act = (node < n);
    int beg = 0, end = 0;
    uint2 uself = make_uint2(0u, 0u);
    float di = 0.0f;
    if (act) {
        beg = rs[node]; end = beg + cnt[node];
        uself = h1su2[node * 4 + f4];   // issue early (independent)
        di = dinv[node];
    }
    float4 acc = make_float4(0.f, 0.f, 0.f, 0.f);
    int e = beg + g4;
    for (; e + 28 < end; e += 32) {
        int s0 = ss[e],      s1 = ss[e + 4],  s2 = ss[e + 8],  s3 = ss[e + 12];
        int s4 = ss[e + 16], s5 = ss[e + 20], s6 = ss[e + 24], s7 = ss[e + 28];
        uint2 u0 = h1su2[s0 * 4 + f4], u1 = h1su2[s1 * 4 + f4];
        uint2 u2 = h1su2[s2 * 4 + f4], u3 = h1su2[s3 * 4 + f4];
        uint2 u4 = h1su2[s4 * 4 + f4], u5 = h1su2[s5 * 4 + f4];
        uint2 u6 = h1su2[s6 * 4 + f4], u7 = h1su2[s7 * 4 + f4];
        ACC2(u0) ACC2(u1) ACC2(u2) ACC2(u3) ACC2(u4) ACC2(u5) ACC2(u6) ACC2(u7)
    }
    for (; e + 4 < end; e += 8) {
        int s0 = ss[e], s1 = ss[e + 4];
        uint2 u0 = h1su2[s0 * 4 + f4], u1 = h1su2[s1 * 4 + f4];
        ACC2(u0) ACC2(u1)
    }
    if (e < end) {
        uint2 u0 = h1su2[ss[e] * 4 + f4];
        ACC2(u0)
    }
#undef ACC2
    // reduce across 4 edge-groups (lane bits 2,3)
    acc.x += __shfl_xor(acc.x, 4, 64); acc.y += __shfl_xor(acc.y, 4, 64);
    acc.z += __shfl_xor(acc.z, 4, 64); acc.w += __shfl_xor(acc.w, 4, 64);
    acc.x += __shfl_xor(acc.x, 8, 64); acc.y += __shfl_xor(acc.y, 8, 64);
    acc.z += __shfl_xor(acc.z, 8, 64); acc.w += __shfl_xor(acc.w, 8, 64);
    float2 sa = unpack_bf16x2(uself.x), sb = unpack_bf16x2(uself.y);  // self-loop (0 inactive)
    acc.x += sa.x; acc.y += sa.y; acc.z += sb.x; acc.w += sb.y;
    // g row broadcast into 16 regs: lane with f4=j holds features 4j..4j+3
    float gg[FH];
#pragma unroll
    for (int j = 0; j < 4; ++j) {
        gg[4 * j]     = __shfl(acc.x, j, 4);
        gg[4 * j + 1] = __shfl(acc.y, j, 4);
        gg[4 * j + 2] = __shfl(acc.z, j, 4);
        gg[4 * j + 3] = __shfl(acc.w, j, 4);
    }
    // pass 1: columns l16, l16+16
    float w0[FH], w1[FH];
#pragma unroll
    for (int j = 0; j < FH; ++j) {
        w0[j] = W2[j * FO + l16];
        w1[j] = W2[j * FO + l16 + 16];
    }
    float o0 = 0.0f, o1 = 0.0f;
#pragma unroll
    for (int j = 0; j < FH; ++j) {
        o0 = fmaf(gg[j], w0[j], o0);
        o1 = fmaf(gg[j], w1[j], o1);
    }
    // pass 2: columns l16+32, l16+48 (reuse w0/w1 regs)
#pragma unroll
    for (int j = 0; j < FH; ++j) {
        w0[j] = W2[j * FO + l16 + 32];
        w1[j] = W2[j * FO + l16 + 48];
    }
    float o2 = 0.0f, o3 = 0.0f;
#pragma unroll
    for (int j = 0; j < FH; ++j) {
        o2 = fmaf(gg[j], w0[j], o2);
        o3 = fmaf(gg[j], w1[j], o3);
    }
    float v0 = fmaf(di, o0, b2[l16]);
    float v1 = fmaf(di, o1, b2[l16 + 16]);
    float v2 = fmaf(di, o2, b2[l16 + 32]);
    float v3 = fmaf(di, o3, b2[l16 + 48]);
    // log_softmax over 64 outputs = 4 regs x 16 lanes (xor offsets < 16 stay in group)
    float m = fmaxf(fmaxf(v0, v1), fmaxf(v2, v3));
#pragma unroll
    for (int off = 8; off >= 1; off >>= 1) m = fmaxf(m, __shfl_xor(m, off, 64));
    float ex = __expf(v0 - m) + __expf(v1 - m) + __expf(v2 - m) + __expf(v3 - m);
#pragma unroll
    for (int off = 8; off >= 1; off >>= 1) ex += __shfl_xor(ex, off, 64);
    float lse = m + __logf(ex);
    if (act) {
        float* orow = out + (long long)node * FO;
        orow[l16]      = v0 - lse;
        orow[l16 + 16] = v1 - lse;
        orow[l16 + 32] = v2 - lse;
        orow[l16 + 48] = v3 - lse;
    }
}

extern "C" void kernel_launch(void* const* d_in, const int* in_sizes, int n_in,
                              void* d_out, int out_size, void* d_ws, size_t ws_size,
                              hipStream_t stream) {
    const float* x  = (const float*)d_in[0];
    const int*   ei = (const int*)d_in[1];
    const float* W1 = (const float*)d_in[2];
    const float* b1 = (const float*)d_in[3];
    const float* W2 = (const float*)d_in[4];
    const float* b2 = (const float*)d_in[5];
    float* out = (float*)d_out;

    int N = in_sizes[0] / FIN;   // 100000
    int E = in_sizes[1] / 2;     // 3200000
    const int* src = ei;
    const int* dst = ei + E;
    int nb = (N + GB - 1) / GB;  // 782

    // slab size per bucket: mean + 25% + 1024 (>20 sigma for uniform dst), 16-rounded,
    // clamped to the LDS staging capacity of k_nsg
    int slab = (E + nb - 1) / nb;
    slab = slab + slab / 4 + 1024;
    slab = (slab + 15) & ~15;
    if (slab > SLABMAX) slab = SLABMAX;
    long long slabtot = (long long)nb * slab;

    // workspace (4B units), hs1u/h1su FIRST (16B-aligned):
    //   hs1u[8N] | h1su[8N] | bfill[1024] | counts[N] | row_start[N]
    //   | sorted_src[nb*slab] | bedge[nb*slab] | dinv[N]
    unsigned* hs1u  = (unsigned*)d_ws;
    unsigned* h1su  = hs1u + 8LL * N;
    int* bfill      = (int*)(h1su + 8LL * N);
    int* counts     = bfill + MAXNB;
    int* row_start  = counts + N;
    int* sorted_src = row_start + N;
    int* bedge      = sorted_src + slabtot;
    float* dinv     = (float*)(bedge + slabtot);

    hipMemsetAsync(bfill, 0, MAXNB * sizeof(int), stream);
    k_bscatter<<<(E + CHUNK - 1) / CHUNK, 1024, 0, stream>>>(src, dst, bfill, bedge, E, slab);
    k_nsg<<<nb, 512, 0, stream>>>(bfill, bedge, x, W1, sorted_src, counts, row_start,
                                  dinv, (uint2*)hs1u, N, slab);
    k_gather1<<<(N + 15) / 16, 256, 0, stream>>>(row_start, counts, sorted_src,
                                                 (const uint2*)hs1u, dinv, b1, (uint2*)h1su, N);
    k_agg2f<<<(N + 15) / 16, 256, 0, stream>>>(row_start, counts, sorted_src,
                                               (const uint2*)h1su, dinv, W2, b2, out, N);
}

// Round 13
// 212.376 us; speedup vs baseline: 1.0327x; 1.0145x over previous
//
#include <hip/hip_runtime.h>

#define FIN 128
#define FH  16
#define FO  64
#define GB  128        // nodes per bucket (pow2: bucket = dst>>7)
#define MAXNB 1024     // max buckets (N <= 131072)
#define CHUNK 8192     // edges per block in bscatter (32 KB LDS stage; 391 blocks -> all CUs busy)
#define SLABMAX 8192   // max slab entries staged in LDS by k_nsg (32 KB per buffer)

__device__ __forceinline__ unsigned pack_bf16x2(float a, float b) {
    unsigned ua = __float_as_uint(a), ub = __float_as_uint(b);
    ua = (ua + 0x7fffu + ((ua >> 16) & 1u)) >> 16;          // RNE
    ub = (ub + 0x7fffu + ((ub >> 16) & 1u)) >> 16;
    return ua | (ub << 16);
}

__device__ __forceinline__ float2 unpack_bf16x2(unsigned u) {
    float2 r;
    r.x = __uint_as_float(u << 16);
    r.y = __uint_as_float(u & 0xffff0000u);
    return r;
}

// ---------- A: slab-reserving chunk-local LDS bucket-sort, shfl-scan (proven round-9) ----------
// bucket b owns slab [b*slab, (b+1)*slab).  pack: (dst & 127) << 17 | src  (src < 2^17)
__global__ __launch_bounds__(1024) void k_bscatter(const int* __restrict__ src,
                                                   const int* __restrict__ dst,
                                                   int* __restrict__ bfill,
                                                   int* __restrict__ bedge,
                                                   int E, int slab) {
    __shared__ int h[MAXNB];      // chunk bucket counts -> fill counters (4 KB)
    __shared__ int wtot[16];      // per-wave scan totals
    __shared__ int stage[CHUNK];  // 32 KB
    int t = threadIdx.x;
    int lane = t & 63, w = t >> 6;
    int c0 = blockIdx.x * CHUNK;
    int c1 = min(c0 + CHUNK, E);

    // 1) chunk histogram (int4 edge reads; c0 is a multiple of 4)
    h[t] = 0;
    __syncthreads();
    const int4* dst4 = (const int4*)dst;
    const int4* src4 = (const int4*)src;
    int i4b = c0 >> 2;
    int i4e = (c0 + ((c1 - c0) & ~3)) >> 2;
    for (int i = i4b + t; i < i4e; i += 1024) {
        int4 d = dst4[i];
        atomicAdd(&h[d.x >> 7], 1);
        atomicAdd(&h[d.y >> 7], 1);
        atomicAdd(&h[d.z >> 7], 1);
        atomicAdd(&h[d.w >> 7], 1);
    }
    for (int e = (i4e << 2) + t; e < c1; e += 1024)
        atomicAdd(&h[dst[e] >> 7], 1);
    __syncthreads();

    // 2) exclusive scan over 1024 buckets: wave shfl-scan + cross-wave fixup (2 barriers)
    int a = h[t];
    int incl = a;
#pragma unroll
    for (int off = 1; off < 64; off <<= 1) {
        int u = __shfl_up(incl, off, 64);
        if (lane >= off) incl += u;
    }
    if (lane == 63) wtot[w] = incl;
    __syncthreads();
    int woff = 0;
    for (int j = 0; j < w; ++j) woff += wtot[j];
    int lo = woff + incl - a;

    // 3) reserve slab range directly, clamp overflow
    int r = 0;
    if (a) r = atomicAdd(&bfill[t], a);
    int navail = slab - r; if (navail < 0) navail = 0;
    int hi = lo + min(a, navail);
    h[t] = lo;
    __syncthreads();

    // 4) place packed edges at chunk-local rank (int4 edge reads)
    for (int i = i4b + t; i < i4e; i += 1024) {
        int4 d = dst4[i];
        int4 s = src4[i];
        int p;
        p = atomicAdd(&h[d.x >> 7], 1); stage[p] = ((d.x & 127) << 17) | s.x;
        p = atomicAdd(&h[d.y >> 7], 1); stage[p] = ((d.y & 127) << 17) | s.y;
        p = atomicAdd(&h[d.z >> 7], 1); stage[p] = ((d.z & 127) << 17) | s.z;
        p = atomicAdd(&h[d.w >> 7], 1); stage[p] = ((d.w & 127) << 17) | s.w;
    }
    for (int e = (i4e << 2) + t; e < c1; e += 1024) {
        int d = dst[e];
        int p = atomicAdd(&h[d >> 7], 1);
        stage[p] = ((d & 127) << 17) | src[e];
    }
    __syncthreads();

    // 5) write-out: each thread streams its own bucket's run, int4-vectorized
    int db = t * slab + r - lo;   // bedge[db + p] for p in [lo, hi)
    int p = lo;
    for (; p < hi && ((db + p) & 3); ++p) bedge[db + p] = stage[p];
    for (; p + 3 < hi; p += 4) {
        int4 v;
        v.x = stage[p]; v.y = stage[p + 1]; v.z = stage[p + 2]; v.w = stage[p + 3];
        *(int4*)(bedge + db + p) = v;
    }
    for (; p < hi; ++p) bedge[db + p] = stage[p];
}

// ---------- B: fused nsort + layer-1 GEMM; slab staged in LDS, sorted in LDS (proven round-9) ----------
__global__ __launch_bounds__(512) void k_nsg(const int* __restrict__ bfill,
                                             const int* __restrict__ bedge,
                                             const float* __restrict__ x,
                                             const float* __restrict__ W1,
                                             int* __restrict__ sorted_src,
                                             int* __restrict__ counts,
                                             int* __restrict__ row_start,
                                             float* __restrict__ dinv,
                                             uint2* __restrict__ hs1u2,
                                             int N, int slab) {
    __shared__ int4 stageL4[SLABMAX / 4];  // 32 KB raw slab
    __shared__ int4 stage24[SLABMAX / 4];  // 32 KB node-sorted src
    __shared__ int hist[GB];
    __shared__ int fill[GB];
    __shared__ float dinvL[GB];
    __shared__ int wtot2[2];
    __shared__ float4 w4[FIN * FH / 4];    // 8 KB
    int* stageL = (int*)stageL4;
    int* stage2 = (int*)stage24;
    int t = threadIdx.x, b = blockIdx.x;
    int lane = t & 63, w = t >> 6;
    int base = b << 7;
    int nn = min(GB, N - base);
    if (nn <= 0) return;

    int ebeg = b * slab;
    int cnt0 = min(bfill[b], slab);
    int c4 = cnt0 >> 2;

    // stage slab -> LDS (coalesced int4); also W1 -> LDS; hist init
    const int4* g4 = (const int4*)(bedge + ebeg);   // ebeg 16B-aligned (slab % 16 == 0)
    for (int i = t; i < c4; i += 512) stageL4[i] = g4[i];
    for (int e = (c4 << 2) + t; e < cnt0; e += 512) stageL[e] = bedge[ebeg + e];
    if (t < GB) hist[t] = 0;
    for (int i = t; i < FIN * FH / 4; i += 512) w4[i] = ((const float4*)W1)[i];
    __syncthreads();

    // histogram from LDS
    for (int i = t; i < c4; i += 512) {
        int4 v = stageL4[i];
        atomicAdd(&hist[v.x >> 17], 1);
        atomicAdd(&hist[v.y >> 17], 1);
        atomicAdd(&hist[v.z >> 17], 1);
        atomicAdd(&hist[v.w >> 17], 1);
    }
    for (int e = (c4 << 2) + t; e < cnt0; e += 512)
        atomicAdd(&hist[stageL[e] >> 17], 1);
    __syncthreads();

    // exclusive scan over 128 counts: wave shfl-scan (threads 0..127 = 2 waves) + fixup
    int c = (t < GB) ? hist[t] : 0;
    int incl = c;
#pragma unroll
    for (int off = 1; off < 64; off <<= 1) {
        int u = __shfl_up(incl, off, 64);
        if (lane >= off) incl += u;
    }
    if (t < GB && lane == 63) wtot2[w] = incl;
    __syncthreads();
    int excl = incl - c + ((w == 1 && t < GB) ? wtot2[0] : 0);
    if (t < nn) {
        counts[base + t] = c;
        row_start[base + t] = ebeg + excl;
        float dv = rsqrtf((float)(c + 1));
        dinv[base + t] = dv;
        dinvL[t] = dv;
        fill[t] = excl;        // LOCAL offset into stage2
    }
    __syncthreads();

    // node-scatter within LDS (random LDS writes, cheap)
    for (int i = t; i < c4; i += 512) {
        int4 v = stageL4[i];
        int p;
        p = atomicAdd(&fill[v.x >> 17], 1); stage2[p] = v.x & 0x1FFFF;
        p = atomicAdd(&fill[v.y >> 17], 1); stage2[p] = v.y & 0x1FFFF;
        p = atomicAdd(&fill[v.z >> 17], 1); stage2[p] = v.z & 0x1FFFF;
        p = atomicAdd(&fill[v.w >> 17], 1); stage2[p] = v.w & 0x1FFFF;
    }
    for (int e = (c4 << 2) + t; e < cnt0; e += 512) {
        int v = stageL[e];
        int p = atomicAdd(&fill[v >> 17], 1);
        stage2[p] = v & 0x1FFFF;
    }
    __syncthreads();

    // stream sorted_src out coalesced (int4)
    int4* o4 = (int4*)(sorted_src + ebeg);
    for (int i = t; i < c4; i += 512) o4[i] = stage24[i];
    for (int e = (c4 << 2) + t; e < cnt0; e += 512) sorted_src[ebeg + e] = stage2[e];

    // ---- phase 2: gemm1, 1 row x 4 features per thread (no barrier needed: w4/dinvL ready) ----
    int fg = t & 3, rg = t >> 2;           // rg: 0..127
    if (rg >= nn) return;
    int r0 = base + rg;
    const float4* xa4 = (const float4*)(x + (long long)r0 * FIN);
    float4 a0 = make_float4(0.f, 0.f, 0.f, 0.f);
#pragma unroll 4
    for (int k4 = 0; k4 < FIN / 4; ++k4) {
        float4 xa = xa4[k4];
        const float4* wp = &w4[k4 * 16 + fg];
        float4 w0 = wp[0], w1 = wp[4], w2 = wp[8], w3 = wp[12];
        a0.x = fmaf(xa.x, w0.x, a0.x); a0.y = fmaf(xa.x, w0.y, a0.y);
        a0.z = fmaf(xa.x, w0.z, a0.z); a0.w = fmaf(xa.x, w0.w, a0.w);
        a0.x = fmaf(xa.y, w1.x, a0.x); a0.y = fmaf(xa.y, w1.y, a0.y);
        a0.z = fmaf(xa.y, w1.z, a0.z); a0.w = fmaf(xa.y, w1.w, a0.w);
        a0.x = fmaf(xa.z, w2.x, a0.x); a0.y = fmaf(xa.z, w2.y, a0.y);
        a0.z = fmaf(xa.z, w2.z, a0.z); a0.w = fmaf(xa.z, w2.w, a0.w);
        a0.x = fmaf(xa.w, w3.x, a0.x); a0.y = fmaf(xa.w, w3.y, a0.y);
        a0.z = fmaf(xa.w, w3.z, a0.z); a0.w = fmaf(xa.w, w3.w, a0.w);
    }
    float d0 = dinvL[rg];
    uint2 o0;
    o0.x = pack_bf16x2(a0.x * d0, a0.y * d0);
    o0.y = pack_bf16x2(a0.z * d0, a0.w * d0);
    hs1u2[r0 * 4 + fg] = o0;
}

// ---------- layer 1 gather: 4 nodes per wave (proven round-8/9) ----------
__global__ __launch_bounds__(256) void k_gather1(const int* __restrict__ rs,
                                                 const int* __restrict__ cnt,
                                                 const int* __restrict__ ss,
                                                 const unsigned* __restrict__ hs1u,
                                                 const float* __restrict__ dinv,
                                                 const float* __restrict__ b1,
                                                 unsigned* __restrict__ h1su, int n) {
    int t = threadIdx.x;
    int lane = t & 63;
    int l16 = lane & 15, g2 = l16 >> 3, f2 = l16 & 7;
    int node = blockIdx.x * 16 + ((t >> 6) << 2) + (lane >> 4);
    bool act = (node < n);
    int beg = 0, end = 0;
    unsigned uself = 0;
    float di = 0.0f;
    if (act) {
        beg = rs[node]; end = beg + cnt[node];
        uself = hs1u[node * 8 + f2];   // issue early (independent)
        di = dinv[node];
    }
    float ax = 0.0f, ay = 0.0f;
    int e = beg + g2;
    for (; e + 14 < end; e += 16) {
        int s0 = ss[e],      s1 = ss[e + 2],  s2 = ss[e + 4],  s3 = ss[e + 6];
        int s4 = ss[e + 8],  s5 = ss[e + 10], s6 = ss[e + 12], s7 = ss[e + 14];
        unsigned u0 = hs1u[s0 * 8 + f2], u1 = hs1u[s1 * 8 + f2];
        unsigned u2 = hs1u[s2 * 8 + f2], u3 = hs1u[s3 * 8 + f2];
        unsigned u4 = hs1u[s4 * 8 + f2], u5 = hs1u[s5 * 8 + f2];
        unsigned u6 = hs1u[s6 * 8 + f2], u7 = hs1u[s7 * 8 + f2];
        float2 p0 = unpack_bf16x2(u0), p1 = unpack_bf16x2(u1);
        float2 p2 = unpack_bf16x2(u2), p3 = unpack_bf16x2(u3);
        float2 p4 = unpack_bf16x2(u4), p5 = unpack_bf16x2(u5);
        float2 p6 = unpack_bf16x2(u6), p7 = unpack_bf16x2(u7);
        ax += ((p0.x + p1.x) + (p2.x + p3.x)) + ((p4.x + p5.x) + (p6.x + p7.x));
        ay += ((p0.y + p1.y) + (p2.y + p3.y)) + ((p4.y + p5.y) + (p6.y + p7.y));
    }
    for (; e + 6 < end; e += 8) {
        int s0 = ss[e], s1 = ss[e + 2], s2 = ss[e + 4], s3 = ss[e + 6];
        unsigned u0 = hs1u[s0 * 8 + f2], u1 = hs1u[s1 * 8 + f2];
        unsigned u2 = hs1u[s2 * 8 + f2], u3 = hs1u[s3 * 8 + f2];
        float2 p0 = unpack_bf16x2(u0), p1 = unpack_bf16x2(u1);
        float2 p2 = unpack_bf16x2(u2), p3 = unpack_bf16x2(u3);
        ax += (p0.x + p1.x) + (p2.x + p3.x);
        ay += (p0.y + p1.y) + (p2.y + p3.y);
    }
    for (; e + 2 < end; e += 4) {
        int s0 = ss[e], s1 = ss[e + 2];
        unsigned u0 = hs1u[s0 * 8 + f2], u1 = hs1u[s1 * 8 + f2];
        float2 p0 = unpack_bf16x2(u0), p1 = unpack_bf16x2(u1);
        ax += p0.x + p1.x; ay += p0.y + p1.y;
    }
    if (e < end) {
        float2 p = unpack_bf16x2(hs1u[ss[e] * 8 + f2]);
        ax += p.x; ay += p.y;
    }
    // reduce across 2 groups (lane bit 3 -- stays within each 16-lane node-group)
    ax += __shfl_xor(ax, 8, 64);  ay += __shfl_xor(ay, 8, 64);
    if (act) {
        float2 s = unpack_bf16x2(uself);  // self-loop
        ax += s.x; ay += s.y;
        float2 bb = ((const float2*)b1)[f2];
        float v0 = fmaxf(fmaf(di, ax, bb.x), 0.0f) * di;
        float v1 = fmaxf(fmaf(di, ay, bb.y), 0.0f) * di;
        if (l16 < 8) h1su[node * 8 + f2] = pack_bf16x2(v0, v1);
    }
}

// ---------- layer 2: 4 nodes per wave; gather + (g @ W2)*dinv + b2 -> log_softmax ----------
// CHANGE vs round 9: W2 + b2 staged in LDS at block entry (barrier BEFORE the gather, so
// no cross-wave coupling of divergent gather tails); epilogue FMAs read LDS (same-address
// broadcast across the 4 node-groups, conflict-free). Removes the 64 post-gather VMEM loads
// and the 32-register w0/w1 arrays.
__global__ __launch_bounds__(256) void k_agg2f(const int* __restrict__ rs,
                                               const int* __restrict__ cnt,
                                               const int* __restrict__ ss,
                                               const unsigned* __restrict__ h1su,
                                               const float* __restrict__ dinv,
                                               const float* __restrict__ W2,
                                               const float* __restrict__ b2,
                                               float* __restrict__ out, int n) {
    __shared__ float w2L[FH * FO];  // 4 KB
    __shared__ float b2L[FO];
    int t = threadIdx.x;
    for (int i = t; i < FH * FO; i += 256) w2L[i] = W2[i];
    if (t < FO) b2L[t] = b2[t];
    __syncthreads();   // before gather: all threads reach this unconditionally
    int lane = t & 63;
    int l16 = lane & 15, g2 = l16 >> 3, f2 = l16 & 7;
    int node = blockIdx.x * 16 + ((t >> 6) << 2) + (lane >> 4);
    bool act = (node < n);
    int beg = 0, end = 0;
    unsigned uself = 0;
    float di = 0.0f;
    if (act) {
        beg = rs[node]; end = beg + cnt[node];
        uself = h1su[node * 8 + f2];   // issue early (independent)
        di = dinv[node];
    }
    float ax = 0.0f, ay = 0.0f;
    int e = beg + g2;
    for (; e + 14 < end; e += 16) {
        int s0 = ss[e],      s1 = ss[e + 2],  s2 = ss[e + 4],  s3 = ss[e + 6];
        int s4 = ss[e + 8],  s5 = ss[e + 10], s6 = ss[e + 12], s7 = ss[e + 14];
        unsigned u0 = h1su[s0 * 8 + f2], u1 = h1su[s1 * 8 + f2];
        unsigned u2 = h1su[s2 * 8 + f2], u3 = h1su[s3 * 8 + f2];
        unsigned u4 = h1su[s4 * 8 + f2], u5 = h1su[s5 * 8 + f2];
        unsigned u6 = h1su[s6 * 8 + f2], u7 = h1su[s7 * 8 + f2];
        float2 p0 = unpack_bf16x2(u0), p1 = unpack_bf16x2(u1);
        float2 p2 = unpack_bf16x2(u2), p3 = unpack_bf16x2(u3);
        float2 p4 = unpack_bf16x2(u4), p5 = unpack_bf16x2(u5);
        float2 p6 = unpack_bf16x2(u6), p7 = unpack_bf16x2(u7);
        ax += ((p0.x + p1.x) + (p2.x + p3.x)) + ((p4.x + p5.x) + (p6.x + p7.x));
        ay += ((p0.y + p1.y) + (p2.y + p3.y)) + ((p4.y + p5.y) + (p6.y + p7.y));
    }
    for (; e + 6 < end; e += 8) {
        int s0 = ss[e], s1 = ss[e + 2], s2 = ss[e + 4], s3 = ss[e + 6];
        unsigned u0 = h1su[s0 * 8 + f2], u1 = h1su[s1 * 8 + f2];
        unsigned u2 = h1su[s2 * 8 + f2], u3 = h1su[s3 * 8 + f2];
        float2 p0 = unpack_bf16x2(u0), p1 = unpack_bf16x2(u1);
        float2 p2 = unpack_bf16x2(u2), p3 = unpack_bf16x2(u3);
        ax += (p0.x + p1.x) + (p2.x + p3.x);
        ay += (p0.y + p1.y) + (p2.y + p3.y);
    }
    for (; e + 2 < end; e += 4) {
        int s0 = ss[e], s1 = ss[e + 2];
        unsigned u0 = h1su[s0 * 8 + f2], u1 = h1su[s1 * 8 + f2];
        float2 p0 = unpack_bf16x2(u0), p1 = unpack_bf16x2(u1);
        ax += p0.x + p1.x; ay += p0.y + p1.y;
    }
    if (e < end) {
        float2 p = unpack_bf16x2(h1su[ss[e] * 8 + f2]);
        ax += p.x; ay += p.y;
    }
    // reduce across 2 groups (lane bit 3)
    ax += __shfl_xor(ax, 8, 64);  ay += __shfl_xor(ay, 8, 64);
    float2 s = unpack_bf16x2(uself);  // self-loop (0 for inactive)
    ax += s.x; ay += s.y;
    // g row broadcast into 16 regs (each 8-lane segment holds its node's full row)
    float gg[FH];
#pragma unroll
    for (int j = 0; j < 8; ++j) {
        gg[2 * j]     = __shfl(ax, j, 8);
        gg[2 * j + 1] = __shfl(ay, j, 8);
    }
    // epilogue from LDS: 4 output columns per lane, one pass
    float o0 = 0.0f, o1 = 0.0f, o2 = 0.0f, o3 = 0.0f;
#pragma unroll
    for (int j = 0; j < FH; ++j) {
        float g = gg[j];
        const float* wr = &w2L[j * FO + l16];
        o0 = fmaf(g, wr[0],  o0);
        o1 = fmaf(g, wr[16], o1);
        o2 = fmaf(g, wr[32], o2);
        o3 = fmaf(g, wr[48], o3);
    }
    float v0 = fmaf(di, o0, b2L[l16]);
    float v1 = fmaf(di, o1, b2L[l16 + 16]);
    float v2 = fmaf(di, o2, b2L[l16 + 32]);
    float v3 = fmaf(di, o3, b2L[l16 + 48]);
    // log_softmax over 64 outputs = 4 regs x 16 lanes (xor offsets < 16 stay in group)
    float m = fmaxf(fmaxf(v0, v1), fmaxf(v2, v3));
#pragma unroll
    for (int off = 8; off >= 1; off >>= 1) m = fmaxf(m, __shfl_xor(m, off, 64));
    float ex = __expf(v0 - m) + __expf(v1 - m) + __expf(v2 - m) + __expf(v3 - m);
#pragma unroll
    for (int off = 8; off >= 1; off >>= 1) ex += __shfl_xor(ex, off, 64);
    float lse = m + __logf(ex);
    if (act) {
        float* orow = out + (long long)node * FO;
        orow[l16]      = v0 - lse;
        orow[l16 + 16] = v1 - lse;
        orow[l16 + 32] = v2 - lse;
        orow[l16 + 48] = v3 - lse;
    }
}

extern "C" void kernel_launch(void* const* d_in, const int* in_sizes, int n_in,
                              void* d_out, int out_size, void* d_ws, size_t ws_size,
                              hipStream_t stream) {
    const float* x  = (const float*)d_in[0];
    const int*   ei = (const int*)d_in[1];
    const float* W1 = (const float*)d_in[2];
    const float* b1 = (const float*)d_in[3];
    const float* W2 = (const float*)d_in[4];
    const float* b2 = (const float*)d_in[5];
    float* out = (float*)d_out;

    int N = in_sizes[0] / FIN;   // 100000
    int E = in_sizes[1] / 2;     // 3200000
    const int* src = ei;
    const int* dst = ei + E;
    int nb = (N + GB - 1) / GB;  // 782

    // slab size per bucket: mean + 25% + 1024 (>20 sigma for uniform dst), 16-rounded,
    // clamped to the LDS staging capacity of k_nsg
    int slab = (E + nb - 1) / nb;
    slab = slab + slab / 4 + 1024;
    slab = (slab + 15) & ~15;
    if (slab > SLABMAX) slab = SLABMAX;
    long long slabtot = (long long)nb * slab;

    // workspace (4B units), hs1u/h1su FIRST (16B-aligned):
    //   hs1u[8N] | h1su[8N] | bfill[1024] | counts[N] | row_start[N]
    //   | sorted_src[nb*slab] | bedge[nb*slab] | dinv[N]
    unsigned* hs1u  = (unsigned*)d_ws;
    unsigned* h1su  = hs1u + 8LL * N;
    int* bfill      = (int*)(h1su + 8LL * N);
    int* counts     = bfill + MAXNB;
    int* row_start  = counts + N;
    int* sorted_src = row_start + N;
    int* bedge      = sorted_src + slabtot;
    float* dinv     = (float*)(bedge + slabtot);

    hipMemsetAsync(bfill, 0, MAXNB * sizeof(int), stream);
    k_bscatter<<<(E + CHUNK - 1) / CHUNK, 1024, 0, stream>>>(src, dst, bfill, bedge, E, slab);
    k_nsg<<<nb, 512, 0, stream>>>(bfill, bedge, x, W1, sorted_src, counts, row_start,
                                  dinv, (uint2*)hs1u, N, slab);
    k_gather1<<<(N + 15) / 16, 256, 0, stream>>>(row_start, counts, sorted_src, hs1u, dinv, b1, h1su, N);
    k_agg2f<<<(N + 15) / 16, 256, 0, stream>>>(row_start, counts, sorted_src, h1su, dinv, W2, b2, out, N);
}